// Round 8
// baseline (92.020 us; speedup 1.0000x reference)
//
#include <hip/hip_runtime.h>

constexpr int EMB    = 300;
constexpr int EMB4   = 75;     // EMB / 4 (float4 chunks per row)
constexpr int HIDDEN = 512;
constexpr int SEQ    = 512;
constexpr int BATCH  = 1024;
constexpr int NBUK   = 32;     // vocab buckets
constexpr int BDIV   = 1563;   // ceil(50000/32)
constexpr int GFC1   = 16;     // batches per fc1 block

__device__ __forceinline__ float4 f4add(float4 a, float4 b) {
    return make_float4(a.x + b.x, a.y + b.y, a.z + b.z, a.w + b.w);
}

// ---------------- Kernel 1: prep = bucketize (blocks 0..127) + length-sort ---
// Blocks 0..127: stable 32-bucket counting sort of 8 batches each (wave/batch,
// ballot-based, deterministic — verified since R4). Block 128: bitonic sort of
// (len<<10|b) keys -> sortperm (deterministic: unique keys, fixed network).
__global__ __launch_bounds__(512) void prep_kernel(
    const int* __restrict__ text,      // [SEQ, BATCH]
    const int* __restrict__ lengths,   // [BATCH]
    int* __restrict__ btok,            // [BATCH, SEQ]
    int* __restrict__ boff,            // [BATCH, NBUK+1]
    int* __restrict__ sortperm)        // [BATCH]
{
    if (blockIdx.x < 128) {
        const int wave = threadIdx.x >> 6;
        const int lane = threadIdx.x & 63;
        const int b    = blockIdx.x * 8 + wave;
        const int len  = lengths[b];
        const unsigned long long ltmask = (1ull << lane) - 1ull;

        int cnt = 0;
#pragma unroll
        for (int c = 0; c < 8; ++c) {
            const int s = c * 64 + lane;
            int k = NBUK;
            if (s < len) k = text[(size_t)s * BATCH + b] / BDIV;
            for (int kk = 0; kk < NBUK; ++kk) {
                const unsigned long long m = __ballot(k == kk);
                if (lane == kk) cnt += __popcll(m);
            }
        }
        int incl = cnt;
#pragma unroll
        for (int off = 1; off < 32; off <<= 1) {
            const int v = __shfl_up(incl, off);
            if (lane >= off && lane < NBUK) incl += v;
        }
        const int excl = incl - cnt;
        if (lane < NBUK)  boff[b * (NBUK + 1) + lane] = excl;
        if (lane == NBUK - 1) boff[b * (NBUK + 1) + NBUK] = incl;

        int base = excl;
#pragma unroll
        for (int c = 0; c < 8; ++c) {
            const int s = c * 64 + lane;
            int tok = 0, k = NBUK;
            if (s < len) { tok = text[(size_t)s * BATCH + b]; k = tok / BDIV; }
            unsigned long long mym = 0;
            int chunkcnt = 0;
            for (int kk = 0; kk < NBUK; ++kk) {
                const unsigned long long m = __ballot(k == kk);
                if (k == kk) mym = m;
                if (lane == kk) chunkcnt = __popcll(m);
            }
            const int rank = __popcll(mym & ltmask);
            const int pos  = __shfl(base, k) + rank;
            if (s < len) btok[(size_t)b * SEQ + pos] = tok;
            base += chunkcnt;
        }
    } else {
        // bitonic sort of 1024 keys with 512 threads
        __shared__ int key[1024];
        for (int i = threadIdx.x; i < 1024; i += 512)
            key[i] = (lengths[i] << 10) | i;
        __syncthreads();
        for (int k = 2; k <= 1024; k <<= 1) {
            for (int j = k >> 1; j > 0; j >>= 1) {
                const int t = threadIdx.x;
                const int i = ((t & ~(j - 1)) << 1) | (t & (j - 1));
                const int p = i | j;
                const bool up = ((i & k) == 0);
                const int a = key[i], c = key[p];
                if ((a > c) == up) { key[i] = c; key[p] = a; }
                __syncthreads();
            }
        }
        for (int i = threadIdx.x; i < 1024; i += 512)
            sortperm[i] = key[i] & 1023;
    }
}

// ---------------- Kernel 2: pool v8 — lockstep vocab sweep -------------------
// 512 blocks (exactly 2/CU, all co-resident). Block q owns the length-
// complementary pair (sorted[q], sorted[1023-q]) -> per-block work ~513 tokens
// (near-constant), so ALL blocks sweep vocab buckets 0..31 in lockstep ->
// instantaneous working set ~ one vocab band -> L2-resident gathers.
// 640 threads = 8 groups x 80 lanes; group j takes positions j, j+8, ... of
// each bucket segment. Writes pooled (mean) directly — no partials.
__global__ __launch_bounds__(640) void pool_kernel(
    const int* __restrict__ btok,      // [BATCH, SEQ] bucket-sorted
    const int* __restrict__ boff,      // [BATCH, NBUK+1]
    const int* __restrict__ lengths,   // [BATCH]
    const int* __restrict__ sortperm,  // [BATCH]
    const float* __restrict__ emb,     // [VOCAB, EMB]
    float* __restrict__ pooled)        // [BATCH, EMB]
{
    __shared__ int    toksL[2][SEQ];     // 4 KB
    __shared__ int    boffL[2][NBUK + 1];
    __shared__ int    binfo[4];          // bA, bB, lenA, lenB
    __shared__ float4 red[8][80];        // 10.2 KB

    const int tid = threadIdx.x;
    const int q   = blockIdx.x;

    if (tid < 2) {
        const int b = sortperm[tid == 0 ? q : (1023 - q)];
        binfo[tid]     = b;
        binfo[2 + tid] = lengths[b];
    }
    __syncthreads();

    for (int i = tid; i < 2 * (NBUK + 1); i += 640) {
        const int g = i / (NBUK + 1), k = i - g * (NBUK + 1);
        boffL[g][k] = boff[binfo[g] * (NBUK + 1) + k];
    }
    for (int g = 0; g < 2; ++g) {
        const int n  = binfo[2 + g];
        const int bb = binfo[g];
        for (int t = tid; t < n; t += 640)
            toksL[g][t] = btok[(size_t)bb * SEQ + t];
    }
    __syncthreads();

    const int grp = tid / 80;
    const int c   = tid % 80;
    float4 A0 = make_float4(0.f, 0.f, 0.f, 0.f);
    float4 A1 = A0;

    if (c < EMB4) {
        const float4* e4 = (const float4*)emb;   // row stride EMB4
        for (int k = 0; k < NBUK; ++k) {
            int lo = boffL[0][k], hi = boffL[0][k + 1];
            for (int p = lo + grp; p < hi; p += 8)
                A0 = f4add(A0, e4[(size_t)toksL[0][p] * EMB4 + c]);
            lo = boffL[1][k]; hi = boffL[1][k + 1];
            for (int p = lo + grp; p < hi; p += 8)
                A1 = f4add(A1, e4[(size_t)toksL[1][p] * EMB4 + c]);
        }
    }

    // reduce 8 groups, write mean
    red[grp][c] = A0;
    __syncthreads();
    if (grp == 0 && c < EMB4) {
        float4 s = red[0][c];
#pragma unroll
        for (int g = 1; g < 8; ++g) s = f4add(s, red[g][c]);
        const float inv = 1.0f / (float)binfo[2];
        s.x *= inv; s.y *= inv; s.z *= inv; s.w *= inv;
        ((float4*)(pooled + (size_t)binfo[0] * EMB))[c] = s;
    }
    __syncthreads();
    red[grp][c] = A1;
    __syncthreads();
    if (grp == 0 && c < EMB4) {
        float4 s = red[0][c];
#pragma unroll
        for (int g = 1; g < 8; ++g) s = f4add(s, red[g][c]);
        const float inv = 1.0f / (float)binfo[3];
        s.x *= inv; s.y *= inv; s.z *= inv; s.w *= inv;
        ((float4*)(pooled + (size_t)binfo[1] * EMB))[c] = s;
    }
}

// ---------------- Kernel 3: fc1 + relu (reads pooled directly) ---------------
__global__ __launch_bounds__(512) void fc1_kernel(
    const float* __restrict__ pooled,  // [BATCH, EMB] (already mean)
    const float* __restrict__ W1,      // [EMB, HIDDEN]
    const float* __restrict__ b1,      // [HIDDEN]
    float* __restrict__ hbuf)          // [BATCH, HIDDEN]
{
    __shared__ float4 pQ[GFC1 / 4][EMB];   // 19.2 KB
    const int b0  = blockIdx.x * GFC1;
    const int tid = threadIdx.x;

    float* pQf = (float*)pQ;
    for (int i = tid; i < EMB * GFC1; i += 512) {
        const int g = i / EMB;
        const int e = i - g * EMB;
        pQf[((g >> 2) * EMB + e) * 4 + (g & 3)] = pooled[(size_t)(b0 + g) * EMB + e];
    }
    __syncthreads();

    const int j  = blockIdx.y * 128 + (tid & 127);
    const int gs = tid >> 7;
    const float bias = b1[j];
    float4 acc = make_float4(bias, bias, bias, bias);

    for (int e = 0; e < EMB; e += 10) {
        const float w0 = W1[(size_t)(e + 0) * HIDDEN + j];
        const float w1 = W1[(size_t)(e + 1) * HIDDEN + j];
        const float w2 = W1[(size_t)(e + 2) * HIDDEN + j];
        const float w3 = W1[(size_t)(e + 3) * HIDDEN + j];
        const float w4 = W1[(size_t)(e + 4) * HIDDEN + j];
        const float w5 = W1[(size_t)(e + 5) * HIDDEN + j];
        const float w6 = W1[(size_t)(e + 6) * HIDDEN + j];
        const float w7 = W1[(size_t)(e + 7) * HIDDEN + j];
        const float w8 = W1[(size_t)(e + 8) * HIDDEN + j];
        const float w9 = W1[(size_t)(e + 9) * HIDDEN + j];
        const float4 p0 = pQ[gs][e + 0];
        const float4 p1 = pQ[gs][e + 1];
        const float4 p2 = pQ[gs][e + 2];
        const float4 p3 = pQ[gs][e + 3];
        const float4 p4 = pQ[gs][e + 4];
        const float4 p5 = pQ[gs][e + 5];
        const float4 p6 = pQ[gs][e + 6];
        const float4 p7 = pQ[gs][e + 7];
        const float4 p8 = pQ[gs][e + 8];
        const float4 p9 = pQ[gs][e + 9];
        acc.x += p0.x * w0 + p1.x * w1 + p2.x * w2 + p3.x * w3 + p4.x * w4
               + p5.x * w5 + p6.x * w6 + p7.x * w7 + p8.x * w8 + p9.x * w9;
        acc.y += p0.y * w0 + p1.y * w1 + p2.y * w2 + p3.y * w3 + p4.y * w4
               + p5.y * w5 + p6.y * w6 + p7.y * w7 + p8.y * w8 + p9.y * w9;
        acc.z += p0.z * w0 + p1.z * w1 + p2.z * w2 + p3.z * w3 + p4.z * w4
               + p5.z * w5 + p6.z * w6 + p7.z * w7 + p8.z * w8 + p9.z * w9;
        acc.w += p0.w * w0 + p1.w * w1 + p2.w * w2 + p3.w * w3 + p4.w * w4
               + p5.w * w5 + p6.w * w6 + p7.w * w7 + p8.w * w8 + p9.w * w9;
    }
    const int bb = b0 + gs * 4;
    hbuf[(size_t)(bb + 0) * HIDDEN + j] = fmaxf(acc.x, 0.f);
    hbuf[(size_t)(bb + 1) * HIDDEN + j] = fmaxf(acc.y, 0.f);
    hbuf[(size_t)(bb + 2) * HIDDEN + j] = fmaxf(acc.z, 0.f);
    hbuf[(size_t)(bb + 3) * HIDDEN + j] = fmaxf(acc.w, 0.f);
}

// ---------------- Kernel 4: fc2 (wave-per-row dot, unchanged) ----------------
__global__ __launch_bounds__(256) void fc2_kernel(
    const float* __restrict__ hbuf,    // [BATCH, HIDDEN]
    const float* __restrict__ W2,      // [HIDDEN, 2]
    const float* __restrict__ b2,      // [2]
    float* __restrict__ out)           // [BATCH, 2]
{
    const int wave = threadIdx.x >> 6;
    const int lane = threadIdx.x & 63;
    const int b    = blockIdx.x * 4 + wave;

    const float4* hrow = (const float4*)(hbuf + (size_t)b * HIDDEN);
    const float4* W2v  = (const float4*)W2;
    float s0 = 0.f, s1 = 0.f;
#pragma unroll
    for (int qq = 0; qq < 2; ++qq) {
        const int c = lane + qq * 64;
        const float4 h  = hrow[c];
        const float4 wA = W2v[2 * c + 0];
        const float4 wB = W2v[2 * c + 1];
        s0 += h.x * wA.x + h.y * wA.z + h.z * wB.x + h.w * wB.z;
        s1 += h.x * wA.y + h.y * wA.w + h.z * wB.y + h.w * wB.w;
    }
#pragma unroll
    for (int off = 32; off > 0; off >>= 1) {
        s0 += __shfl_down(s0, off);
        s1 += __shfl_down(s1, off);
    }
    if (lane == 0) {
        out[b * 2 + 0] = s0 + b2[0];
        out[b * 2 + 1] = s1 + b2[1];
    }
}

extern "C" void kernel_launch(void* const* d_in, const int* in_sizes, int n_in,
                              void* d_out, int out_size, void* d_ws, size_t ws_size,
                              hipStream_t stream) {
    const int*   text    = (const int*)d_in[0];
    const int*   lengths = (const int*)d_in[1];
    const float* emb     = (const float*)d_in[2];
    const float* W1      = (const float*)d_in[3];
    const float* b1      = (const float*)d_in[4];
    const float* W2      = (const float*)d_in[5];
    const float* b2      = (const float*)d_in[6];
    float*       out     = (float*)d_out;

    char* ws = (char*)d_ws;
    const size_t btokBytes = (size_t)BATCH * SEQ * sizeof(int);           // 2 MB
    const size_t boffBytes = (size_t)BATCH * (NBUK + 1) * sizeof(int);    // 132 KB
    const size_t spBytes   = (size_t)BATCH * sizeof(int);                 // 4 KB
    const size_t poolBytes = (size_t)BATCH * EMB * sizeof(float);         // 1.2 MB

    int*   btok     = (int*)ws;
    int*   boff     = (int*)(ws + btokBytes);
    int*   sortperm = (int*)(ws + btokBytes + boffBytes);
    float* pooled   = (float*)(ws + btokBytes + boffBytes + spBytes);
    float* hbuf     = (float*)(ws + btokBytes + boffBytes + spBytes + poolBytes);

    prep_kernel<<<129, 512, 0, stream>>>(text, lengths, btok, boff, sortperm);
    pool_kernel<<<BATCH / 2, 640, 0, stream>>>(btok, boff, lengths, sortperm, emb, pooled);
    fc1_kernel<<<dim3(BATCH / GFC1, HIDDEN / 128), 512, 0, stream>>>(pooled, W1, b1, hbuf);
    fc2_kernel<<<BATCH / 4, 256, 0, stream>>>(hbuf, W2, b2, out);
}

// Round 9
// 75.066 us; speedup vs baseline: 1.2258x; 1.2258x over previous
//
#include <hip/hip_runtime.h>

typedef float f32x4 __attribute__((ext_vector_type(4)));

constexpr int EMB    = 300;
constexpr int EMB4   = 75;     // EMB / 4 (float4 chunks per row)
constexpr int HIDDEN = 512;
constexpr int SEQ    = 512;
constexpr int BATCH  = 1024;
constexpr int NBUK   = 32;     // vocab buckets
constexpr int BDIV   = 1563;   // ceil(50000/32)
constexpr int PB     = 4;      // batches per pool block
constexpr int GFC1   = 16;     // batches per mlp block

// ---------------- Kernel 1: bucketize v2 (single pass, 6-bit ballot) ---------
// 4 waves = 4 batches per block. Stable counting sort into 32 vocab buckets.
// Per chunk: 6 ballots give the same-bucket match mask; rank = popc(mask&lt);
// the rank-0 lane publishes the chunk count to LDS hist. Chunk-prefix +
// bucket-prefix then give the stable position. Output bitwise-identical to
// the verified R4 bucketize.
__global__ __launch_bounds__(256) void bucketize_kernel(
    const int* __restrict__ text,      // [SEQ, BATCH]
    const int* __restrict__ lengths,   // [BATCH]
    int* __restrict__ btok,            // [BATCH, SEQ]
    int* __restrict__ boff)            // [BATCH, NBUK+1]
{
    __shared__ int4 tstage[SEQ];           // text[s][b0..b0+3], 8 KB
    __shared__ int  hist[4][8][NBUK + 2];  // per-wave, per-chunk counts -> prefixes

    const int tid  = threadIdx.x;
    const int wave = tid >> 6;
    const int lane = tid & 63;
    const int b0   = blockIdx.x * 4;
    const int b    = b0 + wave;
    const int len  = lengths[b];
    const unsigned long long lt = (1ull << lane) - 1ull;

    for (int s = tid; s < SEQ; s += 256)
        tstage[s] = *(const int4*)&text[(size_t)s * BATCH + b0];
    for (int i = tid; i < 4 * 8 * (NBUK + 2); i += 256)
        ((int*)hist)[i] = 0;
    __syncthreads();

    int tokv[8], kv[8], rkv[8];
#pragma unroll
    for (int c = 0; c < 8; ++c) {
        const int s      = c * 64 + lane;
        const bool valid = s < len;
        const int tok = valid ? ((const int*)&tstage[s])[wave] : 0;
        const int k   = valid ? tok / BDIV : NBUK;   // NBUK=32 marks padding
        unsigned long long mm = ~0ull;
#pragma unroll
        for (int bit = 0; bit < 6; ++bit) {
            const unsigned long long bl = __ballot((k >> bit) & 1);
            mm &= ((k >> bit) & 1) ? bl : ~bl;
        }
        const int rk = __popcll(mm & lt);
        tokv[c] = tok; kv[c] = k; rkv[c] = rk;
        if (valid && rk == 0) hist[wave][c][k] = __popcll(mm);
    }
    __syncthreads();

    // in-place exclusive chunk-prefix per bucket (lane == bucket), total in tot
    int tot = 0;
    if (lane < NBUK) {
#pragma unroll
        for (int c = 0; c < 8; ++c) {
            const int t = hist[wave][c][lane];
            hist[wave][c][lane] = tot;
            tot += t;
        }
    }
    // exclusive prefix over buckets (lanes 0..31)
    int incl = tot;
#pragma unroll
    for (int off = 1; off < 32; off <<= 1) {
        const int v = __shfl_up(incl, off);
        if (lane >= off && lane < NBUK) incl += v;
    }
    const int excl = incl - tot;
    if (lane < NBUK)      boff[b * (NBUK + 1) + lane] = excl;
    if (lane == NBUK - 1) boff[b * (NBUK + 1) + NBUK] = incl;
    __syncthreads();

    // scatter (stable): pos = bucketBase + chunkPrefix + rankInChunk
#pragma unroll
    for (int c = 0; c < 8; ++c) {
        const int s  = c * 64 + lane;
        const int k  = kv[c];
        const int bb = __shfl(excl, k);            // k<32 for valid lanes
        const int pos = bb + hist[wave][c][k] + rkv[c];
        if (s < len) btok[(size_t)b * SEQ + pos] = tokv[c];
    }
}

// ---------------- asm: 8 independent row-chunk gathers, one wait -------------
__device__ __forceinline__ void gather8(
    const f32x4* a0, const f32x4* a1, const f32x4* a2, const f32x4* a3,
    const f32x4* a4, const f32x4* a5, const f32x4* a6, const f32x4* a7,
    f32x4& v0, f32x4& v1, f32x4& v2, f32x4& v3,
    f32x4& v4, f32x4& v5, f32x4& v6, f32x4& v7)
{
    asm volatile(
        "global_load_dwordx4 %0, %8, off\n\t"
        "global_load_dwordx4 %1, %9, off\n\t"
        "global_load_dwordx4 %2, %10, off\n\t"
        "global_load_dwordx4 %3, %11, off\n\t"
        "global_load_dwordx4 %4, %12, off\n\t"
        "global_load_dwordx4 %5, %13, off\n\t"
        "global_load_dwordx4 %6, %14, off\n\t"
        "global_load_dwordx4 %7, %15, off\n\t"
        "s_waitcnt vmcnt(0)"
        : "=&v"(v0), "=&v"(v1), "=&v"(v2), "=&v"(v3),
          "=&v"(v4), "=&v"(v5), "=&v"(v6), "=&v"(v7)
        : "v"(a0), "v"(a1), "v"(a2), "v"(a3),
          "v"(a4), "v"(a5), "v"(a6), "v"(a7));
}

// ---------------- Kernel 2: pool (R6 structure + forced-ILP gather) ----------
__global__ __launch_bounds__(320) void pool_kernel(
    const int* __restrict__ btok,      // [BATCH, SEQ] bucket-grouped
    const int* __restrict__ boff,      // [BATCH, NBUK+1]
    const float* __restrict__ emb,     // [VOCAB, EMB]
    float* __restrict__ partial,       // [NX, BATCH, EMB]
    int NX)
{
    const int x  = blockIdx.x % NX;    // slot ~ XCD (round-robin dispatch)
    const int b0 = (blockIdx.x / NX) * PB;
    const int NJ = NBUK / NX;

    __shared__ int toks[PB][SEQ];
    __shared__ int seg[PB][2];         // lo, n

    if (threadIdx.x < PB) {
        const int b  = b0 + threadIdx.x;
        const int lo = boff[b * (NBUK + 1) + x * NJ];
        const int hi = boff[b * (NBUK + 1) + x * NJ + NJ];
        seg[threadIdx.x][0] = lo;
        seg[threadIdx.x][1] = hi - lo;
    }
    __syncthreads();

    for (int g = 0; g < PB; ++g) {
        const int lo = seg[g][0], n = seg[g][1];
        for (int t = threadIdx.x; t < n; t += 320)
            toks[g][t] = btok[(size_t)(b0 + g) * SEQ + lo + t];
    }
    __syncthreads();

    const int g = threadIdx.x / 80;
    const int c = threadIdx.x % 80;
    if (c < EMB4) {
        const int n = seg[g][1];
        const f32x4* e4 = (const f32x4*)emb;     // row stride EMB4
        f32x4 A = {0.f, 0.f, 0.f, 0.f};
        f32x4 B = A;
        int i = 0;
        for (; i + 8 <= n; i += 8) {
            const int4 ta = *(const int4*)&toks[g][i];
            const int4 tb = *(const int4*)&toks[g][i + 4];
            const f32x4* a0 = e4 + (size_t)ta.x * EMB4 + c;
            const f32x4* a1 = e4 + (size_t)ta.y * EMB4 + c;
            const f32x4* a2 = e4 + (size_t)ta.z * EMB4 + c;
            const f32x4* a3 = e4 + (size_t)ta.w * EMB4 + c;
            const f32x4* a4 = e4 + (size_t)tb.x * EMB4 + c;
            const f32x4* a5 = e4 + (size_t)tb.y * EMB4 + c;
            const f32x4* a6 = e4 + (size_t)tb.z * EMB4 + c;
            const f32x4* a7 = e4 + (size_t)tb.w * EMB4 + c;
            f32x4 v0, v1, v2, v3, v4, v5, v6, v7;
            gather8(a0, a1, a2, a3, a4, a5, a6, a7,
                    v0, v1, v2, v3, v4, v5, v6, v7);
            A += (v0 + v1) + (v2 + v3);
            B += (v4 + v5) + (v6 + v7);
        }
        for (; i < n; ++i)
            A += e4[(size_t)toks[g][i] * EMB4 + c];
        A += B;
        ((f32x4*)(partial + ((size_t)x * BATCH + b0 + g) * EMB))[c] = A;
    }
}

// ---------------- Kernel 3: fused combine + fc1 + relu + fc2 -----------------
template<int NX>
__global__ __launch_bounds__(512) void mlp_kernel(
    const float* __restrict__ partial, // [NX, BATCH, EMB]
    const int* __restrict__ lengths,   // [BATCH]
    const float* __restrict__ W1,      // [EMB, HIDDEN]
    const float* __restrict__ b1,      // [HIDDEN]
    const float* __restrict__ W2,      // [HIDDEN, 2]
    const float* __restrict__ b2,      // [2]
    float* __restrict__ out)           // [BATCH, 2]
{
    __shared__ f32x4 pQ[GFC1 / 4][EMB];    // 19.2 KB
    __shared__ float hsh[GFC1][HIDDEN];    // 32 KB

    const int b0  = blockIdx.x * GFC1;
    const int tid = threadIdx.x;

    float* pQf = (float*)pQ;
    for (int i = tid; i < EMB * GFC1; i += 512) {
        const int g = i / EMB;
        const int e = i - g * EMB;
        float s = 0.f;
#pragma unroll
        for (int xx = 0; xx < NX; ++xx)
            s += partial[((size_t)xx * BATCH + b0 + g) * EMB + e];
        pQf[((g >> 2) * EMB + e) * 4 + (g & 3)] = s / (float)lengths[b0 + g];
    }
    __syncthreads();

    const int j = tid;                     // HIDDEN == blockDim
    const float bias = b1[j];
    f32x4 acc[4];
#pragma unroll
    for (int q = 0; q < 4; ++q) acc[q] = (f32x4){bias, bias, bias, bias};

#pragma unroll 5
    for (int e = 0; e < EMB; ++e) {
        const float w = W1[(size_t)e * HIDDEN + j];
#pragma unroll
        for (int q = 0; q < 4; ++q) acc[q] += pQ[q][e] * w;
    }
#pragma unroll
    for (int q = 0; q < 4; ++q) {
        hsh[q * 4 + 0][j] = fmaxf(acc[q].x, 0.f);
        hsh[q * 4 + 1][j] = fmaxf(acc[q].y, 0.f);
        hsh[q * 4 + 2][j] = fmaxf(acc[q].z, 0.f);
        hsh[q * 4 + 3][j] = fmaxf(acc[q].w, 0.f);
    }
    __syncthreads();

    const int w    = tid >> 6;
    const int lane = tid & 63;
    const f32x4* W2v = (const f32x4*)W2;
#pragma unroll
    for (int rr = 0; rr < 2; ++rr) {
        const int r = w * 2 + rr;
        float s0 = 0.f, s1 = 0.f;
#pragma unroll
        for (int q = 0; q < 2; ++q) {
            const int cc = lane + q * 64;
            const f32x4 hv = *(const f32x4*)&hsh[r][4 * cc];
            const f32x4 wA = W2v[2 * cc + 0];
            const f32x4 wB = W2v[2 * cc + 1];
            s0 += hv.x * wA.x + hv.y * wA.z + hv.z * wB.x + hv.w * wB.z;
            s1 += hv.x * wA.y + hv.y * wA.w + hv.z * wB.y + hv.w * wB.w;
        }
#pragma unroll
        for (int off = 32; off > 0; off >>= 1) {
            s0 += __shfl_down(s0, off);
            s1 += __shfl_down(s1, off);
        }
        if (lane == 0) {
            out[(b0 + r) * 2 + 0] = s0 + b2[0];
            out[(b0 + r) * 2 + 1] = s1 + b2[1];
        }
    }
}

extern "C" void kernel_launch(void* const* d_in, const int* in_sizes, int n_in,
                              void* d_out, int out_size, void* d_ws, size_t ws_size,
                              hipStream_t stream) {
    const int*   text    = (const int*)d_in[0];
    const int*   lengths = (const int*)d_in[1];
    const float* emb     = (const float*)d_in[2];
    const float* W1      = (const float*)d_in[3];
    const float* b1      = (const float*)d_in[4];
    const float* W2      = (const float*)d_in[5];
    const float* b2      = (const float*)d_in[6];
    float*       out     = (float*)d_out;

    char* ws = (char*)d_ws;
    const size_t btokBytes = (size_t)BATCH * SEQ * sizeof(int);           // 2 MB
    const size_t boffBytes = (size_t)BATCH * (NBUK + 1) * sizeof(int);    // 132 KB
    const size_t poolBytes = (size_t)BATCH * EMB * sizeof(float);         // 1.2 MB

    int*   btok    = (int*)ws;
    int*   boff    = (int*)(ws + btokBytes);
    float* partial = (float*)(ws + btokBytes + boffBytes);

    const size_t fixed = btokBytes + boffBytes;
    int NX = 1;
    if      (ws_size >= fixed + 8 * poolBytes) NX = 8;
    else if (ws_size >= fixed + 4 * poolBytes) NX = 4;
    else if (ws_size >= fixed + 2 * poolBytes) NX = 2;

    bucketize_kernel<<<BATCH / 4, 256, 0, stream>>>(text, lengths, btok, boff);
    pool_kernel<<<NX * (BATCH / PB), 320, 0, stream>>>(btok, boff, emb, partial, NX);

    switch (NX) {
        case 8:  mlp_kernel<8><<<BATCH / GFC1, 512, 0, stream>>>(partial, lengths, W1, b1, W2, b2, out); break;
        case 4:  mlp_kernel<4><<<BATCH / GFC1, 512, 0, stream>>>(partial, lengths, W1, b1, W2, b2, out); break;
        case 2:  mlp_kernel<2><<<BATCH / GFC1, 512, 0, stream>>>(partial, lengths, W1, b1, W2, b2, out); break;
        default: mlp_kernel<1><<<BATCH / GFC1, 512, 0, stream>>>(partial, lengths, W1, b1, W2, b2, out); break;
    }
}

// Round 10
// 61.478 us; speedup vs baseline: 1.4968x; 1.2210x over previous
//
#include <hip/hip_runtime.h>

typedef float f32x4 __attribute__((ext_vector_type(4)));

constexpr int EMB    = 300;
constexpr int EMB4   = 75;     // EMB/4 (8-B bf16 chunks or 16-B f32 chunks per row)
constexpr int HIDDEN = 512;
constexpr int SEQ    = 512;
constexpr int BATCH  = 1024;
constexpr int VOCAB  = 50000;
constexpr int NBUK   = 32;     // vocab buckets
constexpr int BDIV   = 1563;   // ceil(50000/32)
constexpr int PB     = 4;      // batches per pool block
constexpr int GMLP   = 8;      // batches per mlp block
constexpr int NCONV  = 1792;   // convert blocks inside prep (256+1792 = 2048 total)
constexpr int ELEM4  = VOCAB * EMB / 4;   // 3,750,000 float4s in emb

__device__ __forceinline__ unsigned short f2bf(float x) {   // RNE f32->bf16
    unsigned u = __float_as_uint(x);
    u += 0x7fffu + ((u >> 16) & 1u);
    return (unsigned short)(u >> 16);
}

// ---------------- Kernel 1: prep = bucketize (blocks 0..255) + f32->bf16 -----
// Blocks 0..255: bucketize v2 (verified R9, bitwise-identical output).
// Blocks 256..2047: grid-stride convert of emb (60 MB read, 30 MB write).
__global__ __launch_bounds__(256) void prep_kernel(
    const int* __restrict__ text,      // [SEQ, BATCH]
    const int* __restrict__ lengths,   // [BATCH]
    const float* __restrict__ emb,     // [VOCAB, EMB]
    int* __restrict__ btok,            // [BATCH, SEQ]
    int* __restrict__ boff,            // [BATCH, NBUK+1]
    unsigned short* __restrict__ ebf,  // [VOCAB, EMB] bf16
    int doConv)
{
    __shared__ int4 tstage[SEQ];           // 8 KB
    __shared__ int  hist[4][8][NBUK + 2];

    const int tid = threadIdx.x;

    if (blockIdx.x >= 256) {               // ---- convert lane ----
        if (!doConv) return;
        const float4* src = (const float4*)emb;
        ushort4*      dst = (ushort4*)ebf;
        const int gtid = (blockIdx.x - 256) * 256 + tid;
        for (int i = gtid; i < ELEM4; i += NCONV * 256) {
            const float4 v = src[i];
            ushort4 o;
            o.x = f2bf(v.x); o.y = f2bf(v.y);
            o.z = f2bf(v.z); o.w = f2bf(v.w);
            dst[i] = o;
        }
        return;
    }

    // ---- bucketize lane (4 waves = 4 batches) ----
    const int wave = tid >> 6;
    const int lane = tid & 63;
    const int b0   = blockIdx.x * 4;
    const int b    = b0 + wave;
    const int len  = lengths[b];
    const unsigned long long lt = (1ull << lane) - 1ull;

    for (int s = tid; s < SEQ; s += 256)
        tstage[s] = *(const int4*)&text[(size_t)s * BATCH + b0];
    for (int i = tid; i < 4 * 8 * (NBUK + 2); i += 256)
        ((int*)hist)[i] = 0;
    __syncthreads();

    int tokv[8], kv[8], rkv[8];
#pragma unroll
    for (int c = 0; c < 8; ++c) {
        const int s      = c * 64 + lane;
        const bool valid = s < len;
        const int tok = valid ? ((const int*)&tstage[s])[wave] : 0;
        const int k   = valid ? tok / BDIV : NBUK;
        unsigned long long mm = ~0ull;
#pragma unroll
        for (int bit = 0; bit < 6; ++bit) {
            const unsigned long long bl = __ballot((k >> bit) & 1);
            mm &= ((k >> bit) & 1) ? bl : ~bl;
        }
        const int rk = __popcll(mm & lt);
        tokv[c] = tok; kv[c] = k; rkv[c] = rk;
        if (valid && rk == 0) hist[wave][c][k] = __popcll(mm);
    }
    __syncthreads();

    int tot = 0;
    if (lane < NBUK) {
#pragma unroll
        for (int c = 0; c < 8; ++c) {
            const int t = hist[wave][c][lane];
            hist[wave][c][lane] = tot;
            tot += t;
        }
    }
    int incl = tot;
#pragma unroll
    for (int off = 1; off < 32; off <<= 1) {
        const int v = __shfl_up(incl, off);
        if (lane >= off && lane < NBUK) incl += v;
    }
    const int excl = incl - tot;
    if (lane < NBUK)      boff[b * (NBUK + 1) + lane] = excl;
    if (lane == NBUK - 1) boff[b * (NBUK + 1) + NBUK] = incl;
    __syncthreads();

#pragma unroll
    for (int c = 0; c < 8; ++c) {
        const int s  = c * 64 + lane;
        const int k  = kv[c];
        const int bb = __shfl(excl, k);
        const int pos = bb + hist[wave][c][k] + rkv[c];
        if (s < len) btok[(size_t)b * SEQ + pos] = tokv[c];
    }
}

__device__ __forceinline__ f32x4 bf4up(uint2 u) {   // 4 bf16 -> f32x4
    f32x4 r;
    r.x = __uint_as_float(u.x << 16);
    r.y = __uint_as_float(u.x & 0xffff0000u);
    r.z = __uint_as_float(u.y << 16);
    r.w = __uint_as_float(u.y & 0xffff0000u);
    return r;
}

// ---------------- Kernel 2: pool (R6/R9 structure; bf16 or f32 rows) ---------
// Slot x owns contiguous buckets [x*NJ,(x+1)*NJ) (best measured locality).
// BF: lane c reads 8 B (4 bf16) of the 600-B row -> half the bytes AND half
// the cache lines per row vs f32.
template<bool BF>
__global__ __launch_bounds__(320) void pool_kernel(
    const int* __restrict__ btok,      // [BATCH, SEQ] bucket-grouped
    const int* __restrict__ boff,      // [BATCH, NBUK+1]
    const float* __restrict__ emb,     // [VOCAB, EMB] f32
    const unsigned short* __restrict__ ebf, // [VOCAB, EMB] bf16
    float* __restrict__ partial,       // [NX, BATCH, EMB]
    int NX)
{
    const int x  = blockIdx.x % NX;    // slot ~ XCD (round-robin dispatch)
    const int b0 = (blockIdx.x / NX) * PB;
    const int NJ = NBUK / NX;

    __shared__ int toks[PB][SEQ];
    __shared__ int seg[PB][2];

    if (threadIdx.x < PB) {
        const int b  = b0 + threadIdx.x;
        const int lo = boff[b * (NBUK + 1) + x * NJ];
        const int hi = boff[b * (NBUK + 1) + x * NJ + NJ];
        seg[threadIdx.x][0] = lo;
        seg[threadIdx.x][1] = hi - lo;
    }
    __syncthreads();

    for (int g = 0; g < PB; ++g) {
        const int lo = seg[g][0], n = seg[g][1];
        for (int t = threadIdx.x; t < n; t += 320)
            toks[g][t] = btok[(size_t)(b0 + g) * SEQ + lo + t];
    }
    __syncthreads();

    const int g = threadIdx.x / 80;
    const int c = threadIdx.x % 80;
    if (c < EMB4) {
        const int n = seg[g][1];
        f32x4 A = {0.f, 0.f, 0.f, 0.f};
        f32x4 B = A;
        int i = 0;
        if constexpr (BF) {
            const uint2* e2 = (const uint2*)ebf;   // row stride EMB4 uint2s
            for (; i + 4 <= n; i += 4) {
                const int4 t4 = *(const int4*)&toks[g][i];
                const uint2 u0 = e2[(size_t)t4.x * EMB4 + c];
                const uint2 u1 = e2[(size_t)t4.y * EMB4 + c];
                const uint2 u2 = e2[(size_t)t4.z * EMB4 + c];
                const uint2 u3 = e2[(size_t)t4.w * EMB4 + c];
                A += bf4up(u0) + bf4up(u1);
                B += bf4up(u2) + bf4up(u3);
            }
            for (; i < n; ++i)
                A += bf4up(e2[(size_t)toks[g][i] * EMB4 + c]);
        } else {
            const f32x4* e4 = (const f32x4*)emb;   // row stride EMB4 f32x4s
            for (; i + 4 <= n; i += 4) {
                const int4 t4 = *(const int4*)&toks[g][i];
                const f32x4 v0 = e4[(size_t)t4.x * EMB4 + c];
                const f32x4 v1 = e4[(size_t)t4.y * EMB4 + c];
                const f32x4 v2 = e4[(size_t)t4.z * EMB4 + c];
                const f32x4 v3 = e4[(size_t)t4.w * EMB4 + c];
                A += v0 + v1;
                B += v2 + v3;
            }
            for (; i < n; ++i)
                A += e4[(size_t)toks[g][i] * EMB4 + c];
        }
        A += B;
        ((f32x4*)(partial + ((size_t)x * BATCH + b0 + g) * EMB))[c] = A;
    }
}

// ---------------- Kernel 3: fused combine + fc1 + relu + fc2 -----------------
// 128 blocks x 512 thr; block owns 8 batches + full hidden dim. W1 (614 KB)
// is L2-resident -> 78 MB of L2 reads ~ few microseconds.
template<int NX>
__global__ __launch_bounds__(512) void mlp_kernel(
    const float* __restrict__ partial, // [NX, BATCH, EMB]
    const int* __restrict__ lengths,   // [BATCH]
    const float* __restrict__ W1,      // [EMB, HIDDEN]
    const float* __restrict__ b1,      // [HIDDEN]
    const float* __restrict__ W2,      // [HIDDEN, 2]
    const float* __restrict__ b2,      // [2]
    float* __restrict__ out)           // [BATCH, 2]
{
    __shared__ f32x4 pQ[GMLP / 4][EMB];    // 9.6 KB
    __shared__ float hsh[GMLP][HIDDEN];    // 16 KB

    const int b0  = blockIdx.x * GMLP;
    const int tid = threadIdx.x;

    float* pQf = (float*)pQ;
    for (int i = tid; i < EMB * GMLP; i += 512) {
        const int g = i / EMB;
        const int e = i - g * EMB;
        float s = 0.f;
#pragma unroll
        for (int xx = 0; xx < NX; ++xx)
            s += partial[((size_t)xx * BATCH + b0 + g) * EMB + e];
        pQf[((g >> 2) * EMB + e) * 4 + (g & 3)] = s / (float)lengths[b0 + g];
    }
    __syncthreads();

    const int j = tid;                     // HIDDEN == blockDim
    const float bias = b1[j];
    f32x4 acc0 = {bias, bias, bias, bias};
    f32x4 acc1 = acc0;

#pragma unroll 10
    for (int e = 0; e < EMB; ++e) {
        const float w = W1[(size_t)e * HIDDEN + j];
        acc0 += pQ[0][e] * w;
        acc1 += pQ[1][e] * w;
    }
    hsh[0][j] = fmaxf(acc0.x, 0.f);
    hsh[1][j] = fmaxf(acc0.y, 0.f);
    hsh[2][j] = fmaxf(acc0.z, 0.f);
    hsh[3][j] = fmaxf(acc0.w, 0.f);
    hsh[4][j] = fmaxf(acc1.x, 0.f);
    hsh[5][j] = fmaxf(acc1.y, 0.f);
    hsh[6][j] = fmaxf(acc1.z, 0.f);
    hsh[7][j] = fmaxf(acc1.w, 0.f);
    __syncthreads();

    const int w    = tid >> 6;             // 0..7 -> batch row
    const int lane = tid & 63;
    const f32x4* W2v = (const f32x4*)W2;
    float s0 = 0.f, s1 = 0.f;
#pragma unroll
    for (int q = 0; q < 2; ++q) {
        const int cc = lane + q * 64;      // f32x4 chunk of the h row
        const f32x4 hv = *(const f32x4*)&hsh[w][4 * cc];
        const f32x4 wA = W2v[2 * cc + 0];
        const f32x4 wB = W2v[2 * cc + 1];
        s0 += hv.x * wA.x + hv.y * wA.z + hv.z * wB.x + hv.w * wB.z;
        s1 += hv.x * wA.y + hv.y * wA.w + hv.z * wB.y + hv.w * wB.w;
    }
#pragma unroll
    for (int off = 32; off > 0; off >>= 1) {
        s0 += __shfl_down(s0, off);
        s1 += __shfl_down(s1, off);
    }
    if (lane == 0) {
        out[(b0 + w) * 2 + 0] = s0 + b2[0];
        out[(b0 + w) * 2 + 1] = s1 + b2[1];
    }
}

extern "C" void kernel_launch(void* const* d_in, const int* in_sizes, int n_in,
                              void* d_out, int out_size, void* d_ws, size_t ws_size,
                              hipStream_t stream) {
    const int*   text    = (const int*)d_in[0];
    const int*   lengths = (const int*)d_in[1];
    const float* emb     = (const float*)d_in[2];
    const float* W1      = (const float*)d_in[3];
    const float* b1      = (const float*)d_in[4];
    const float* W2      = (const float*)d_in[5];
    const float* b2      = (const float*)d_in[6];
    float*       out     = (float*)d_out;

    char* ws = (char*)d_ws;
    const size_t btokBytes = (size_t)BATCH * SEQ * sizeof(int);            // 2 MB
    const size_t boffBytes = (size_t)BATCH * (NBUK + 1) * sizeof(int);     // 132 KB
    const size_t ebfBytes  = (size_t)VOCAB * EMB * sizeof(unsigned short); // 30 MB
    const size_t poolBytes = (size_t)BATCH * EMB * sizeof(float);          // 1.2 MB

    int* btok = (int*)ws;
    int* boff = (int*)(ws + btokBytes);
    size_t off = btokBytes + boffBytes;
    off = (off + 63) & ~(size_t)63;
    unsigned short* ebf = (unsigned short*)(ws + off);

    const size_t fixedBF = off + ebfBytes;
    bool useBF = false;
    int NX = 1;
    float* partial;
    if (ws_size >= fixedBF + 2 * poolBytes) {
        useBF = true;
        partial = (float*)(ws + fixedBF);
        if      (ws_size >= fixedBF + 8 * poolBytes) NX = 8;
        else if (ws_size >= fixedBF + 4 * poolBytes) NX = 4;
        else                                         NX = 2;
    } else {
        partial = (float*)(ws + off);
        if      (ws_size >= off + 8 * poolBytes) NX = 8;
        else if (ws_size >= off + 4 * poolBytes) NX = 4;
        else if (ws_size >= off + 2 * poolBytes) NX = 2;
    }

    prep_kernel<<<useBF ? 256 + NCONV : 256, 256, 0, stream>>>(
        text, lengths, emb, btok, boff, ebf, useBF ? 1 : 0);

    if (useBF)
        pool_kernel<true><<<NX * (BATCH / PB), 320, 0, stream>>>(btok, boff, emb, ebf, partial, NX);
    else
        pool_kernel<false><<<NX * (BATCH / PB), 320, 0, stream>>>(btok, boff, emb, ebf, partial, NX);

    switch (NX) {
        case 8:  mlp_kernel<8><<<BATCH / GMLP, 512, 0, stream>>>(partial, lengths, W1, b1, W2, b2, out); break;
        case 4:  mlp_kernel<4><<<BATCH / GMLP, 512, 0, stream>>>(partial, lengths, W1, b1, W2, b2, out); break;
        case 2:  mlp_kernel<2><<<BATCH / GMLP, 512, 0, stream>>>(partial, lengths, W1, b1, W2, b2, out); break;
        default: mlp_kernel<1><<<BATCH / GMLP, 512, 0, stream>>>(partial, lengths, W1, b1, W2, b2, out); break;
    }
}